// Round 4
// baseline (653.083 us; speedup 1.0000x reference)
//
#include <hip/hip_runtime.h>

#define BATCH 8192
#define FEAT  4096
#define MID   512
#define EMB   256
#define KCODE 512

typedef _Float16 half8 __attribute__((ext_vector_type(8)));
typedef float floatx4 __attribute__((ext_vector_type(4)));

// Power-of-2 scales; descaled exactly in epilogues.
#define SC_X    512.0f
#define SC_W    4096.0f
#define SC_H    512.0f
#define SC_ENC  4096.0f
#define SC_CODE 4096.0f
#define SC_EMB  4096.0f
#define SC_TM   512.0f
#define DS_G1   (1.0f / (SC_X   * SC_W))
#define DS_G2   (1.0f / (SC_H   * SC_W))
#define DS_G3   (1.0f / (SC_ENC * SC_CODE))
#define DS_D1   (1.0f / (SC_EMB * SC_W))
#define DS_D2   (1.0f / (SC_TM  * SC_W))

#define LSTRIDE 40   // padded LDS row stride (f16 units): 80 B = 20 banks -> min-phase r/w

// ---------------------------------------------------------------------------
// gemm_v2<NT>: C[M,N] = act( A @ B^T * descale + bias )
// Tile 128(M) x 64(N), BK=32, 4 waves of 32x64. NT=3: hi*hi+hi*lo+lo*hi
// (fp32-equivalent); NT=1: hi*hi only (decoder).
//  - A: fp32 (in-register split, aScale) or pre-split f16 hi/lo. Register-
//    staged -> double-buffered padded LDS. ONE barrier per K-iter.
//  - B: pre-split BT hi/lo [N][K]; fragments loaded global->register directly
//    (rows of BT are native B-fragment layout), register-double-buffered.
//  - swz: XCD swizzle so all gridN N-blocks of an M-stripe land on one XCD
//    (A-stripe served from that XCD's L2). Requires 1-D grid, gridM%8==0.
// ---------------------------------------------------------------------------
template<int NT>
__global__ __launch_bounds__(256)
void gemm_v2(const float* __restrict__ Af32,
             const _Float16* __restrict__ Ahg, const _Float16* __restrict__ Alg,
             const _Float16* __restrict__ BTh, const _Float16* __restrict__ BTl,
             const float* __restrict__ bias, float aScale, float descale, int relu,
             float* __restrict__ outF,
             _Float16* __restrict__ outHi, _Float16* __restrict__ outLo,
             float outScale, int M, int N, int K, int swz, int lgN)
{
    __shared__ __align__(16) _Float16 AhB[2][128 * LSTRIDE];
    __shared__ __align__(16) _Float16 AlB[2][128 * LSTRIDE];

    const int tid  = threadIdx.x;
    const int lane = tid & 63;
    const int wave = tid >> 6;
    const int l15  = lane & 15;
    const int quad = lane >> 4;
    const int q8   = quad * 8;

    int bm, bn;
    if (swz) { int b = blockIdx.x; bn = (b >> 3) & ((1 << lgN) - 1);
               bm = ((b >> (3 + lgN)) << 3) | (b & 7); }
    else     { bm = blockIdx.y; bn = blockIdx.x; }
    const int row0 = bm * 128, col0 = bn * 64;

    // A staging: thread t covers row t>>1, k-offset (t&1)*16 (16 elems)
    const int srow = tid >> 1;
    const int sk   = (tid & 1) * 16;
    const size_t aOff = (size_t)(row0 + srow) * K + sk;
    const int lA = srow * LSTRIDE + sk;

    floatx4 acc[2][4] = {};
    float4 fa[4];
    half8  rah[2], ral[2];
    half8  bhA[4], blA[4], bhB[4], blB[4];

    auto stageA = [&](int kt) {
        if (Af32) {
            const float* p = Af32 + aOff + kt;
            fa[0] = *(const float4*)(p);
            fa[1] = *(const float4*)(p + 4);
            fa[2] = *(const float4*)(p + 8);
            fa[3] = *(const float4*)(p + 12);
        } else {
            const _Float16* p = Ahg + aOff + kt;
            rah[0] = *(const half8*)(p);
            rah[1] = *(const half8*)(p + 8);
            if (NT == 3) {
                const _Float16* q = Alg + aOff + kt;
                ral[0] = *(const half8*)(q);
                ral[1] = *(const half8*)(q + 8);
            }
        }
    };

    auto loadB = [&](half8 (&bh)[4], half8 (&bl)[4], int kt) {
        #pragma unroll
        for (int j = 0; j < 4; ++j) {
            size_t o = (size_t)(col0 + j * 16 + l15) * K + kt + q8;
            bh[j] = *(const half8*)(BTh + o);
            if (NT == 3) bl[j] = *(const half8*)(BTl + o);
        }
    };

    auto writeA = [&](_Float16* dAh, _Float16* dAl) {
        if (Af32) {
            const float* f = (const float*)fa;
            half8 hv0, hv1, lv0, lv1;
            #pragma unroll
            for (int e = 0; e < 8; ++e) {
                float v = f[e] * aScale;
                _Float16 h = (_Float16)v;
                hv0[e] = h; lv0[e] = (_Float16)(v - (float)h);
            }
            #pragma unroll
            for (int e = 0; e < 8; ++e) {
                float v = f[8 + e] * aScale;
                _Float16 h = (_Float16)v;
                hv1[e] = h; lv1[e] = (_Float16)(v - (float)h);
            }
            *(half8*)&dAh[lA] = hv0; *(half8*)&dAh[lA + 8] = hv1;
            if (NT == 3) { *(half8*)&dAl[lA] = lv0; *(half8*)&dAl[lA + 8] = lv1; }
        } else {
            *(half8*)&dAh[lA] = rah[0]; *(half8*)&dAh[lA + 8] = rah[1];
            if (NT == 3) { *(half8*)&dAl[lA] = ral[0]; *(half8*)&dAl[lA + 8] = ral[1]; }
        }
    };

    auto compute = [&](const _Float16* bAh, const _Float16* bAl,
                       half8 (&bh)[4], half8 (&bl)[4]) {
        half8 xah[2], xal[2];
        #pragma unroll
        for (int i = 0; i < 2; ++i) {
            int ra = (wave * 32 + i * 16 + l15) * LSTRIDE + q8;
            xah[i] = *(const half8*)&bAh[ra];
            if (NT == 3) xal[i] = *(const half8*)&bAl[ra];
        }
        #pragma unroll
        for (int i = 0; i < 2; ++i)
            #pragma unroll
            for (int j = 0; j < 4; ++j) {
                acc[i][j] = __builtin_amdgcn_mfma_f32_16x16x32_f16(xah[i], bh[j], acc[i][j], 0, 0, 0);
                if (NT == 3) {
                    acc[i][j] = __builtin_amdgcn_mfma_f32_16x16x32_f16(xah[i], bl[j], acc[i][j], 0, 0, 0);
                    acc[i][j] = __builtin_amdgcn_mfma_f32_16x16x32_f16(xal[i], bh[j], acc[i][j], 0, 0, 0);
                }
            }
    };

    const int nIter = K / 32;   // even, >= 2 for all shapes here

    stageA(0);
    loadB(bhA, blA, 0);
    writeA(AhB[0], AlB[0]);
    __syncthreads();

    // peeled iteration 1
    stageA(32);
    loadB(bhB, blB, 32);
    compute(AhB[0], AlB[0], bhA, blA);
    writeA(AhB[1], AlB[1]);
    __syncthreads();

    for (int it = 2; it + 1 < nIter; it += 2) {
        stageA(it * 32);
        loadB(bhA, blA, it * 32);
        compute(AhB[1], AlB[1], bhB, blB);
        writeA(AhB[0], AlB[0]);
        __syncthreads();

        stageA((it + 1) * 32);
        loadB(bhB, blB, (it + 1) * 32);
        compute(AhB[0], AlB[0], bhA, blA);
        writeA(AhB[1], AlB[1]);
        __syncthreads();
    }
    compute(AhB[1], AlB[1], bhB, blB);

    // Epilogue. C/D layout: col = lane&15, row = quad*4 + reg (verified m89).
    #pragma unroll
    for (int j = 0; j < 4; ++j) {
        int col = col0 + j * 16 + l15;
        float bcol = bias ? bias[col] : 0.0f;
        #pragma unroll
        for (int i = 0; i < 2; ++i) {
            #pragma unroll
            for (int t = 0; t < 4; ++t) {
                int r = row0 + wave * 32 + i * 16 + quad * 4 + t;
                float v = acc[i][j][t] * descale + bcol;
                if (relu) v = fmaxf(v, 0.0f);
                size_t o = (size_t)r * N + col;
                if (outF) outF[o] = v;
                if (outHi) {
                    float sv = v * outScale;
                    _Float16 h = (_Float16)sv;
                    outHi[o] = h;
                    outLo[o] = (_Float16)(sv - (float)h);
                }
            }
        }
    }
}

// ---------------------------------------------------------------------------
// Transpose fp32 [R][C] -> scaled f16 hi/lo [C][R]. 32x32 LDS tiles.
// ---------------------------------------------------------------------------
__global__ __launch_bounds__(256)
void transpose_split(const float* __restrict__ src, _Float16* __restrict__ hi,
                     _Float16* __restrict__ lo, float scale, int R, int C)
{
    __shared__ float t[32][33];
    int tx = threadIdx.x & 31, ty = threadIdx.x >> 5;
    int r0 = blockIdx.y * 32, c0 = blockIdx.x * 32;
    #pragma unroll
    for (int p = 0; p < 4; ++p) {
        int r = ty + p * 8;
        t[r][tx] = src[(size_t)(r0 + r) * C + c0 + tx];
    }
    __syncthreads();
    #pragma unroll
    for (int p = 0; p < 4; ++p) {
        int oc = ty + p * 8;
        float v = t[tx][oc] * scale;
        _Float16 h = (_Float16)v;
        size_t o = (size_t)(c0 + oc) * R + r0 + tx;
        hi[o] = h;
        lo[o] = (_Float16)(v - (float)h);
    }
}

// ---------------------------------------------------------------------------
// Normalize codebook rows (fp32 math), emit scaled f16 hi/lo [K][E].
// ---------------------------------------------------------------------------
__global__ __launch_bounds__(256)
void norm_codes(const float* __restrict__ emb, _Float16* __restrict__ cnHi,
                _Float16* __restrict__ cnLo)
{
    int wave = threadIdx.x >> 6;
    int lane = threadIdx.x & 63;
    int c = blockIdx.x * 4 + wave;
    if (c >= KCODE) return;
    const float* er = emb + (size_t)c * EMB;
    float ss = 0.0f;
    #pragma unroll
    for (int k = lane; k < EMB; k += 64) { float v = er[k]; ss += v * v; }
    #pragma unroll
    for (int off = 32; off > 0; off >>= 1) ss += __shfl_down(ss, off, 64);
    ss = __shfl(ss, 0, 64);
    float inv = 1.0f / (sqrtf(ss) + 1e-12f);
    #pragma unroll
    for (int k = lane; k < EMB; k += 64) {
        float v = er[k] * inv * SC_CODE;
        _Float16 h = (_Float16)v;
        cnHi[(size_t)c * EMB + k] = h;
        cnLo[(size_t)c * EMB + k] = (_Float16)(v - (float)h);
    }
}

// ---------------------------------------------------------------------------
// Per-row argmax over S[B,K] -> one-hot, vq_feat gather, index.
// First-index tie-break (numpy argmax semantics).
// ---------------------------------------------------------------------------
__global__ __launch_bounds__(256)
void argmax_vq(const float* __restrict__ S, const float* __restrict__ emb,
               float* __restrict__ onehot, float* __restrict__ vqfeat,
               int* __restrict__ idxOut)
{
    int wave = threadIdx.x >> 6;
    int lane = threadIdx.x & 63;
    int row = blockIdx.x * 4 + wave;
    if (row >= BATCH) return;

    const float* s = S + (size_t)row * KCODE;
    float bestV = -3.402823466e+38f;
    int   bestI = 0;
    #pragma unroll
    for (int c = lane; c < KCODE; c += 64) {
        float v = s[c];
        if (v > bestV) { bestV = v; bestI = c; }
    }
    #pragma unroll
    for (int off = 32; off > 0; off >>= 1) {
        float ov = __shfl_down(bestV, off, 64);
        int   oi = __shfl_down(bestI, off, 64);
        if (ov > bestV || (ov == bestV && oi < bestI)) { bestV = ov; bestI = oi; }
    }
    bestI = __shfl(bestI, 0, 64);
    if (lane == 0) idxOut[row] = bestI;

    float* oh = onehot + (size_t)row * KCODE;
    #pragma unroll
    for (int c = lane; c < KCODE; c += 64) oh[c] = (c == bestI) ? 1.0f : 0.0f;

    const float* er = emb + (size_t)bestI * EMB;
    float* vr = vqfeat + (size_t)row * EMB;
    #pragma unroll
    for (int c = lane; c < EMB; c += 64) vr[c] = er[c];
}

__global__ __launch_bounds__(256)
void gather_decoded(const float* __restrict__ Dcode, const int* __restrict__ idx,
                    float* __restrict__ out)
{
    int row = blockIdx.x;
    int k = idx[row];
    const float4* src = (const float4*)(Dcode + (size_t)k * FEAT);
    float4* dst = (float4*)(out + (size_t)row * FEAT);
    #pragma unroll
    for (int i = threadIdx.x; i < FEAT / 4; i += 256) dst[i] = src[i];
}

__global__ __launch_bounds__(256)
void copy_f4(const float* __restrict__ src, float* __restrict__ dst, int n4)
{
    int i = blockIdx.x * 256 + threadIdx.x;
    if (i < n4) ((float4*)dst)[i] = ((const float4*)src)[i];
}

// ---------------------------------------------------------------------------
extern "C" void kernel_launch(void* const* d_in, const int* in_sizes, int n_in,
                              void* d_out, int out_size, void* d_ws, size_t ws_size,
                              hipStream_t stream)
{
    const float* x      = (const float*)d_in[0];
    const float* enc_w1 = (const float*)d_in[1];
    const float* enc_b1 = (const float*)d_in[2];
    const float* enc_w2 = (const float*)d_in[3];
    const float* enc_b2 = (const float*)d_in[4];
    const float* emb    = (const float*)d_in[5];
    const float* dec_w1 = (const float*)d_in[6];
    const float* dec_b1 = (const float*)d_in[7];
    const float* dec_w2 = (const float*)d_in[8];
    const float* dec_b2 = (const float*)d_in[9];

    float* out = (float*)d_out;
    float* out_encoded = out;
    float* out_vqfeat  = out + (size_t)BATCH * EMB;
    float* out_onehot  = out + (size_t)2 * BATCH * EMB;
    float* out_decoded = out + (size_t)2 * BATCH * EMB + (size_t)BATCH * KCODE;
    float* out_emb     = out_decoded + (size_t)BATCH * FEAT;

    // ------- workspace layout -------
    char* w = (char*)d_ws;
    _Float16* w1T_hi = (_Float16*)w;  w += (size_t)FEAT * MID * 2;
    _Float16* w1T_lo = (_Float16*)w;  w += (size_t)FEAT * MID * 2;
    _Float16* w2T_hi = (_Float16*)w;  w += (size_t)MID * EMB * 2;
    _Float16* w2T_lo = (_Float16*)w;  w += (size_t)MID * EMB * 2;
    _Float16* h_hi   = (_Float16*)w;  w += (size_t)BATCH * MID * 2;
    _Float16* h_lo   = (_Float16*)w;  w += (size_t)BATCH * MID * 2;
    _Float16* enc_hi = (_Float16*)w;  w += (size_t)BATCH * EMB * 2;
    _Float16* enc_lo = (_Float16*)w;  w += (size_t)BATCH * EMB * 2;
    _Float16* cn_hi  = (_Float16*)w;  w += (size_t)KCODE * EMB * 2;
    _Float16* cn_lo  = (_Float16*)w;  w += (size_t)KCODE * EMB * 2;
    _Float16* wd1T_hi= (_Float16*)w;  w += (size_t)MID * EMB * 2;
    _Float16* wd1T_lo= (_Float16*)w;  w += (size_t)MID * EMB * 2;
    _Float16* wd2T_hi= (_Float16*)w;  w += (size_t)FEAT * MID * 2;
    _Float16* wd2T_lo= (_Float16*)w;  w += (size_t)FEAT * MID * 2;
    _Float16* tm_hi  = (_Float16*)w;  w += (size_t)KCODE * MID * 2;
    _Float16* tm_lo  = (_Float16*)w;  w += (size_t)KCODE * MID * 2;
    float*    S      = (float*)w;     w += (size_t)BATCH * KCODE * 4;
    float*    Dc     = (float*)w;     w += (size_t)KCODE * FEAT * 4;
    int*      idx    = (int*)w;

    // --- prep: weight transposes/splits, codebook norm, emb passthrough ---
    transpose_split<<<dim3(MID / 32, FEAT / 32), dim3(256), 0, stream>>>(
        enc_w1, w1T_hi, w1T_lo, SC_W, FEAT, MID);
    transpose_split<<<dim3(EMB / 32, MID / 32), dim3(256), 0, stream>>>(
        enc_w2, w2T_hi, w2T_lo, SC_W, MID, EMB);
    transpose_split<<<dim3(MID / 32, EMB / 32), dim3(256), 0, stream>>>(
        dec_w1, wd1T_hi, wd1T_lo, SC_W, EMB, MID);
    transpose_split<<<dim3(FEAT / 32, MID / 32), dim3(256), 0, stream>>>(
        dec_w2, wd2T_hi, wd2T_lo, SC_W, MID, FEAT);
    norm_codes<<<dim3(KCODE / 4), dim3(256), 0, stream>>>(emb, cn_hi, cn_lo);
    copy_f4<<<dim3((KCODE * EMB / 4 + 255) / 256), dim3(256), 0, stream>>>(
        emb, out_emb, KCODE * EMB / 4);

    // --- G1: h = relu(x @ w1 + b1); 512 blocks (2/CU), XCD swizzle lgN=3
    gemm_v2<3><<<dim3((BATCH / 128) * (MID / 64)), dim3(256), 0, stream>>>(
        x, nullptr, nullptr, w1T_hi, w1T_lo, enc_b1, SC_X, DS_G1, 1,
        nullptr, h_hi, h_lo, SC_H, BATCH, MID, FEAT, 1, 3);

    // --- G2: encoded = h @ w2 + b2; 256 blocks, swizzle lgN=2
    gemm_v2<3><<<dim3((BATCH / 128) * (EMB / 64)), dim3(256), 0, stream>>>(
        nullptr, h_hi, h_lo, w2T_hi, w2T_lo, enc_b2, 0.0f, DS_G2, 0,
        out_encoded, enc_hi, enc_lo, SC_ENC, BATCH, EMB, MID, 1, 2);

    // --- G3: S = encoded @ cn^T; 512 blocks, swizzle lgN=3
    gemm_v2<3><<<dim3((BATCH / 128) * (KCODE / 64)), dim3(256), 0, stream>>>(
        nullptr, enc_hi, enc_lo, cn_hi, cn_lo, nullptr, 0.0f, DS_G3, 0,
        S, nullptr, nullptr, 1.0f, BATCH, KCODE, EMB, 1, 3);

    // --- argmax -> one-hot, vq_feat, idx
    argmax_vq<<<dim3(BATCH / 4), dim3(256), 0, stream>>>(
        S, emb, out_onehot, out_vqfeat, idx);

    // --- decoder on codebook only (512 distinct rows), 1-term f16
    gemm_v2<1><<<dim3(MID / 64, KCODE / 128), dim3(256), 0, stream>>>(
        emb, nullptr, nullptr, wd1T_hi, wd1T_lo, dec_b1, SC_EMB, DS_D1, 1,
        nullptr, tm_hi, tm_lo, SC_TM, KCODE, MID, EMB, 0, 0);
    gemm_v2<1><<<dim3(FEAT / 64, KCODE / 128), dim3(256), 0, stream>>>(
        nullptr, tm_hi, tm_lo, wd2T_hi, wd2T_lo, dec_b2, 0.0f, DS_D2, 1,
        Dc, nullptr, nullptr, 1.0f, KCODE, FEAT, MID, 0, 0);

    // --- decoded[i] = Dcode[idx[i]]
    gather_decoded<<<dim3(BATCH), dim3(256), 0, stream>>>(Dc, idx, out_decoded);
}

// Round 5
// 498.716 us; speedup vs baseline: 1.3095x; 1.3095x over previous
//
#include <hip/hip_runtime.h>

#define BATCH 8192
#define FEAT  4096
#define MID   512
#define EMB   256
#define KCODE 512

typedef _Float16 half8 __attribute__((ext_vector_type(8)));
typedef _Float16 half4v __attribute__((ext_vector_type(4)));
typedef float floatx4 __attribute__((ext_vector_type(4)));

// Power-of-2 scales; descaled exactly in epilogues/reduces.
#define SC_X    512.0f
#define SC_W    4096.0f
#define SC_H    512.0f
#define SC_ENC  4096.0f
#define SC_CODE 4096.0f
#define SC_EMB  4096.0f
#define SC_TM   512.0f
#define DS_G1   (1.0f / (SC_X   * SC_W))
#define DS_G2   (1.0f / (SC_H   * SC_W))
#define DS_D1   (1.0f / (SC_EMB * SC_W))
#define DS_D2   (1.0f / (SC_TM  * SC_W))

#define GLD16(gp, lp)                                                          \
    __builtin_amdgcn_global_load_lds(                                          \
        (const __attribute__((address_space(1))) void*)(gp),                   \
        (__attribute__((address_space(3))) void*)(lp), 16, 0, 0)

// ---------------------------------------------------------------------------
// Split-K m97-style MFMA GEMM. Tile 128x128, BK=32, 4 waves (2x2 of 64x64).
// C = A @ B^T (B pre-split/scaled f16 hi/lo, TRANSPOSED [N][K]).
// NT=3: hi*hi + hi*lo + lo*hi (fp32-equivalent). NT=1: hi only.
// AF32=1: A is fp32, split to scaled f16 hi/lo in-register during staging.
// AF32=0: A pre-split hi/lo, staged via global_load_lds (width 16).
// If partOut != null: raw fp32 accumulators to partOut[ks*M*N + ...] (no
// bias/descale). Else: final epilogue (descale, bias, relu, fp32 / hi-lo out).
// swz: 1-D grid, b -> {m_lo=b&7, ks, n, m_hi}; all n/k-peers of an M-stripe
// share b%8 (same XCD) for L2-shared A; gridM%8==0 required.
// ---------------------------------------------------------------------------
template<int NT, int AF32>
__global__ __launch_bounds__(256)
void gemm_sk(const float* __restrict__ Af32,
             const _Float16* __restrict__ Ahg, const _Float16* __restrict__ Alg,
             const _Float16* __restrict__ BTh, const _Float16* __restrict__ BTl,
             float aScale,
             float* __restrict__ partOut,
             const float* __restrict__ bias, float descale, int relu,
             float* __restrict__ outF, _Float16* __restrict__ outHi,
             _Float16* __restrict__ outLo, float outScale,
             int M, int N, int K, int lgK, int lgN, int swz)
{
    __shared__ _Float16 AhS[128 * 32];
    __shared__ _Float16 BhS[128 * 32];
    __shared__ _Float16 AlS[NT == 3 ? 128 * 32 : 8];
    __shared__ _Float16 BlS[NT == 3 ? 128 * 32 : 8];

    const int tid  = threadIdx.x;
    const int lane = tid & 63;
    const int wave = tid >> 6;
    const int wm = wave >> 1, wn = wave & 1;
    const int l15  = lane & 15;
    const int quad = lane >> 4;
    const int q8   = quad * 8;

    int bm, bn, ks;
    if (swz) {
        int b = blockIdx.x;
        int mlo = b & 7;
        ks = (b >> 3) & ((1 << lgK) - 1);
        bn = (b >> (3 + lgK)) & ((1 << lgN) - 1);
        bm = ((b >> (3 + lgK + lgN)) << 3) | mlo;
    } else { bm = blockIdx.y; bn = blockIdx.x; ks = 0; }
    const int row0 = bm * 128, col0 = bn * 128;
    const int Kslice = K >> lgK;
    const int k0 = ks * Kslice;

    // GLD16 staging coords (covers 64 rows per call; two calls = 128 rows)
    const int sr4 = tid >> 2;
    const int sc4 = (tid & 3) * 8;
    const size_t aB0 = (size_t)(row0 + sr4) * K + sc4;
    const size_t aB1 = (size_t)(row0 + 64 + sr4) * K + sc4;
    const size_t bB0 = (size_t)(col0 + sr4) * K + sc4;
    const size_t bB1 = (size_t)(col0 + 64 + sr4) * K + sc4;
    const int l0 = tid * 8, l1 = 2048 + tid * 8;

    // AF32 staging coords (one pass: 256 threads x 16 elems = 128x32)
    const int sr2 = tid >> 1;
    const int sk2 = (tid & 1) * 16;
    const size_t aOff2 = (size_t)(row0 + sr2) * K + sk2;
    const int lA = sr2 * 32 + sk2;

    floatx4 acc[4][4] = {};

    for (int kt = 0; kt < Kslice; kt += 32) {
        // --- B staging: always GLD16 ---
        GLD16(BTh + bB0 + k0 + kt, &BhS[l0]);
        GLD16(BTh + bB1 + k0 + kt, &BhS[l1]);
        if (NT == 3) {
            GLD16(BTl + bB0 + k0 + kt, &BlS[l0]);
            GLD16(BTl + bB1 + k0 + kt, &BlS[l1]);
        }
        // --- A staging ---
        if (AF32) {
            const float* p = Af32 + aOff2 + k0 + kt;
            float4 f0 = *(const float4*)(p);
            float4 f1 = *(const float4*)(p + 4);
            float4 f2 = *(const float4*)(p + 8);
            float4 f3 = *(const float4*)(p + 12);
            float fv[16] = {f0.x,f0.y,f0.z,f0.w, f1.x,f1.y,f1.z,f1.w,
                            f2.x,f2.y,f2.z,f2.w, f3.x,f3.y,f3.z,f3.w};
            half8 hv0, hv1, lv0, lv1;
            #pragma unroll
            for (int e = 0; e < 8; ++e) {
                float v = fv[e] * aScale;
                _Float16 h = (_Float16)v;
                hv0[e] = h; lv0[e] = (_Float16)(v - (float)h);
            }
            #pragma unroll
            for (int e = 0; e < 8; ++e) {
                float v = fv[8 + e] * aScale;
                _Float16 h = (_Float16)v;
                hv1[e] = h; lv1[e] = (_Float16)(v - (float)h);
            }
            *(half8*)&AhS[lA] = hv0; *(half8*)&AhS[lA + 8] = hv1;
            if (NT == 3) { *(half8*)&AlS[lA] = lv0; *(half8*)&AlS[lA + 8] = lv1; }
        } else {
            GLD16(Ahg + aB0 + k0 + kt, &AhS[l0]);
            GLD16(Ahg + aB1 + k0 + kt, &AhS[l1]);
            if (NT == 3) {
                GLD16(Alg + aB0 + k0 + kt, &AlS[l0]);
                GLD16(Alg + aB1 + k0 + kt, &AlS[l1]);
            }
        }
        __syncthreads();

        half8 ah[4], al4[4], bh[4], bl4[4];
        #pragma unroll
        for (int i = 0; i < 4; ++i) {
            int ra = (wm * 64 + i * 16 + l15) * 32 + q8;
            int rb = (wn * 64 + i * 16 + l15) * 32 + q8;
            ah[i] = *(const half8*)&AhS[ra];
            bh[i] = *(const half8*)&BhS[rb];
            if (NT == 3) {
                al4[i] = *(const half8*)&AlS[ra];
                bl4[i] = *(const half8*)&BlS[rb];
            }
        }
        #pragma unroll
        for (int i = 0; i < 4; ++i)
            #pragma unroll
            for (int j = 0; j < 4; ++j) {
                acc[i][j] = __builtin_amdgcn_mfma_f32_16x16x32_f16(ah[i], bh[j], acc[i][j], 0, 0, 0);
                if (NT == 3) {
                    acc[i][j] = __builtin_amdgcn_mfma_f32_16x16x32_f16(ah[i],  bl4[j], acc[i][j], 0, 0, 0);
                    acc[i][j] = __builtin_amdgcn_mfma_f32_16x16x32_f16(al4[i], bh[j],  acc[i][j], 0, 0, 0);
                }
            }
        __syncthreads();
    }

    // Epilogue. C/D layout: col = lane&15, row = quad*4 + reg (verified m89).
    if (partOut) {
        float* po = partOut + (size_t)ks * M * N;
        #pragma unroll
        for (int j = 0; j < 4; ++j) {
            int col = col0 + wn * 64 + j * 16 + l15;
            #pragma unroll
            for (int i = 0; i < 4; ++i)
                #pragma unroll
                for (int t = 0; t < 4; ++t) {
                    int r = row0 + wm * 64 + i * 16 + quad * 4 + t;
                    po[(size_t)r * N + col] = acc[i][j][t];
                }
        }
    } else {
        #pragma unroll
        for (int j = 0; j < 4; ++j) {
            int col = col0 + wn * 64 + j * 16 + l15;
            float bcol = bias ? bias[col] : 0.0f;
            #pragma unroll
            for (int i = 0; i < 4; ++i)
                #pragma unroll
                for (int t = 0; t < 4; ++t) {
                    int r = row0 + wm * 64 + i * 16 + quad * 4 + t;
                    float v = acc[i][j][t] * descale + bcol;
                    if (relu) v = fmaxf(v, 0.0f);
                    size_t o = (size_t)r * N + col;
                    if (outF) outF[o] = v;
                    if (outHi) {
                        float sv = v * outScale;
                        _Float16 h = (_Float16)sv;
                        outHi[o] = h;
                        outLo[o] = (_Float16)(sv - (float)h);
                    }
                }
        }
    }
}

// ---------------------------------------------------------------------------
// Split-K reduce: out = relu( (sum_s part[s]) * descale + bias ), emitting
// fp32 and/or scaled f16 hi/lo. float4 per thread.
// ---------------------------------------------------------------------------
__global__ __launch_bounds__(256)
void reduce_sk(const float* __restrict__ part, int nSlice, int MN, int N,
               const float* __restrict__ bias, float descale, int relu,
               float* __restrict__ outF, _Float16* __restrict__ outHi,
               _Float16* __restrict__ outLo, float outScale)
{
    int i = blockIdx.x * 256 + threadIdx.x;
    if (i * 4 >= MN) return;
    float4 s = ((const float4*)part)[i];
    for (int sl = 1; sl < nSlice; ++sl) {
        float4 p = ((const float4*)(part + (size_t)sl * MN))[i];
        s.x += p.x; s.y += p.y; s.z += p.z; s.w += p.w;
    }
    int col = (i * 4) % N;
    float v[4] = {s.x, s.y, s.z, s.w};
    #pragma unroll
    for (int e = 0; e < 4; ++e) {
        float t = v[e] * descale + (bias ? bias[col + e] : 0.0f);
        if (relu) t = fmaxf(t, 0.0f);
        v[e] = t;
    }
    if (outF) ((float4*)outF)[i] = *(float4*)v;
    if (outHi) {
        half4v hv, lv;
        #pragma unroll
        for (int e = 0; e < 4; ++e) {
            float sv = v[e] * outScale;
            _Float16 h = (_Float16)sv;
            hv[e] = h;
            lv[e] = (_Float16)(sv - (float)h);
        }
        ((half4v*)outHi)[i] = hv;
        ((half4v*)outLo)[i] = lv;
    }
}

// ---------------------------------------------------------------------------
// Transpose fp32 [R][C] -> scaled f16 hi/lo [C][R]. 32x32 LDS tiles.
// ---------------------------------------------------------------------------
__global__ __launch_bounds__(256)
void transpose_split(const float* __restrict__ src, _Float16* __restrict__ hi,
                     _Float16* __restrict__ lo, float scale, int R, int C)
{
    __shared__ float t[32][33];
    int tx = threadIdx.x & 31, ty = threadIdx.x >> 5;
    int r0 = blockIdx.y * 32, c0 = blockIdx.x * 32;
    #pragma unroll
    for (int p = 0; p < 4; ++p) {
        int r = ty + p * 8;
        t[r][tx] = src[(size_t)(r0 + r) * C + c0 + tx];
    }
    __syncthreads();
    #pragma unroll
    for (int p = 0; p < 4; ++p) {
        int oc = ty + p * 8;
        float v = t[tx][oc] * scale;
        _Float16 h = (_Float16)v;
        size_t o = (size_t)(c0 + oc) * R + r0 + tx;
        hi[o] = h;
        lo[o] = (_Float16)(v - (float)h);
    }
}

// ---------------------------------------------------------------------------
// Normalize codebook rows (fp32 math), emit scaled f16 hi/lo [K][E].
// ---------------------------------------------------------------------------
__global__ __launch_bounds__(256)
void norm_codes(const float* __restrict__ emb, _Float16* __restrict__ cnHi,
                _Float16* __restrict__ cnLo)
{
    int wave = threadIdx.x >> 6;
    int lane = threadIdx.x & 63;
    int c = blockIdx.x * 4 + wave;
    if (c >= KCODE) return;
    const float* er = emb + (size_t)c * EMB;
    float ss = 0.0f;
    #pragma unroll
    for (int k = lane; k < EMB; k += 64) { float v = er[k]; ss += v * v; }
    #pragma unroll
    for (int off = 32; off > 0; off >>= 1) ss += __shfl_down(ss, off, 64);
    ss = __shfl(ss, 0, 64);
    float inv = 1.0f / (sqrtf(ss) + 1e-12f);
    #pragma unroll
    for (int k = lane; k < EMB; k += 64) {
        float v = er[k] * inv * SC_CODE;
        _Float16 h = (_Float16)v;
        cnHi[(size_t)c * EMB + k] = h;
        cnLo[(size_t)c * EMB + k] = (_Float16)(v - (float)h);
    }
}

// ---------------------------------------------------------------------------
// Argmax over sim rows, where sim[row][c] = p0[row][c] + p1[row][c]
// (2 split-K partials; positive common scale is argmax-invariant, so no
// descale). Writes one-hot, vq_feat gather, index. First-index tie-break.
// ---------------------------------------------------------------------------
__global__ __launch_bounds__(256)
void argmax_vq2(const float* __restrict__ part, int MN,
                const float* __restrict__ emb,
                float* __restrict__ onehot, float* __restrict__ vqfeat,
                int* __restrict__ idxOut)
{
    int wave = threadIdx.x >> 6;
    int lane = threadIdx.x & 63;
    int row = blockIdx.x * 4 + wave;
    if (row >= BATCH) return;

    const float* p0 = part + (size_t)row * KCODE;
    const float* p1 = part + (size_t)MN + (size_t)row * KCODE;
    float bestV = -3.402823466e+38f;
    int   bestI = 0;
    #pragma unroll
    for (int c = lane; c < KCODE; c += 64) {
        float v = p0[c] + p1[c];
        if (v > bestV) { bestV = v; bestI = c; }
    }
    #pragma unroll
    for (int off = 32; off > 0; off >>= 1) {
        float ov = __shfl_down(bestV, off, 64);
        int   oi = __shfl_down(bestI, off, 64);
        if (ov > bestV || (ov == bestV && oi < bestI)) { bestV = ov; bestI = oi; }
    }
    bestI = __shfl(bestI, 0, 64);
    if (lane == 0) idxOut[row] = bestI;

    float* oh = onehot + (size_t)row * KCODE;
    #pragma unroll
    for (int c = lane; c < KCODE; c += 64) oh[c] = (c == bestI) ? 1.0f : 0.0f;

    const float* er = emb + (size_t)bestI * EMB;
    float* vr = vqfeat + (size_t)row * EMB;
    #pragma unroll
    for (int c = lane; c < EMB; c += 64) vr[c] = er[c];
}

__global__ __launch_bounds__(256)
void gather_decoded(const float* __restrict__ Dcode, const int* __restrict__ idx,
                    float* __restrict__ out)
{
    int row = blockIdx.x;
    int k = idx[row];
    const float4* src = (const float4*)(Dcode + (size_t)k * FEAT);
    float4* dst = (float4*)(out + (size_t)row * FEAT);
    #pragma unroll
    for (int i = threadIdx.x; i < FEAT / 4; i += 256) dst[i] = src[i];
}

__global__ __launch_bounds__(256)
void copy_f4(const float* __restrict__ src, float* __restrict__ dst, int n4)
{
    int i = blockIdx.x * 256 + threadIdx.x;
    if (i < n4) ((float4*)dst)[i] = ((const float4*)src)[i];
}

// ---------------------------------------------------------------------------
extern "C" void kernel_launch(void* const* d_in, const int* in_sizes, int n_in,
                              void* d_out, int out_size, void* d_ws, size_t ws_size,
                              hipStream_t stream)
{
    const float* x      = (const float*)d_in[0];
    const float* enc_w1 = (const float*)d_in[1];
    const float* enc_b1 = (const float*)d_in[2];
    const float* enc_w2 = (const float*)d_in[3];
    const float* enc_b2 = (const float*)d_in[4];
    const float* emb    = (const float*)d_in[5];
    const float* dec_w1 = (const float*)d_in[6];
    const float* dec_b1 = (const float*)d_in[7];
    const float* dec_w2 = (const float*)d_in[8];
    const float* dec_b2 = (const float*)d_in[9];

    float* out = (float*)d_out;
    float* out_encoded = out;
    float* out_vqfeat  = out + (size_t)BATCH * EMB;
    float* out_onehot  = out + (size_t)2 * BATCH * EMB;
    float* out_decoded = out + (size_t)2 * BATCH * EMB + (size_t)BATCH * KCODE;
    float* out_emb     = out_decoded + (size_t)BATCH * FEAT;

    // ------- workspace layout (~116 MB) -------
    char* w = (char*)d_ws;
    _Float16* w1T_hi = (_Float16*)w;  w += (size_t)FEAT * MID * 2;
    _Float16* w1T_lo = (_Float16*)w;  w += (size_t)FEAT * MID * 2;
    _Float16* w2T_hi = (_Float16*)w;  w += (size_t)MID * EMB * 2;
    _Float16* w2T_lo = (_Float16*)w;  w += (size_t)MID * EMB * 2;
    _Float16* wd1T_hi= (_Float16*)w;  w += (size_t)MID * EMB * 2;
    _Float16* wd1T_lo= (_Float16*)w;  w += (size_t)MID * EMB * 2;
    _Float16* wd2T_hi= (_Float16*)w;  w += (size_t)FEAT * MID * 2;
    _Float16* wd2T_lo= (_Float16*)w;  w += (size_t)FEAT * MID * 2;
    _Float16* h_hi   = (_Float16*)w;  w += (size_t)BATCH * MID * 2;
    _Float16* h_lo   = (_Float16*)w;  w += (size_t)BATCH * MID * 2;
    _Float16* enc_hi = (_Float16*)w;  w += (size_t)BATCH * EMB * 2;
    _Float16* enc_lo = (_Float16*)w;  w += (size_t)BATCH * EMB * 2;
    _Float16* cn_hi  = (_Float16*)w;  w += (size_t)KCODE * EMB * 2;
    _Float16* cn_lo  = (_Float16*)w;  w += (size_t)KCODE * EMB * 2;
    _Float16* tm_hi  = (_Float16*)w;  w += (size_t)KCODE * MID * 2;
    _Float16* tm_lo  = (_Float16*)w;  w += (size_t)KCODE * MID * 2;
    float*    Dc     = (float*)w;     w += (size_t)KCODE * FEAT * 4;
    float*    scr    = (float*)w;     w += (size_t)4 * BATCH * MID * 4;  // 64 MB, reused
    int*      idx    = (int*)w;

    // --- prep: weight transposes/splits, codebook norm, emb passthrough ---
    transpose_split<<<dim3(MID / 32, FEAT / 32), dim3(256), 0, stream>>>(
        enc_w1, w1T_hi, w1T_lo, SC_W, FEAT, MID);
    transpose_split<<<dim3(EMB / 32, MID / 32), dim3(256), 0, stream>>>(
        enc_w2, w2T_hi, w2T_lo, SC_W, MID, EMB);
    transpose_split<<<dim3(MID / 32, EMB / 32), dim3(256), 0, stream>>>(
        dec_w1, wd1T_hi, wd1T_lo, SC_W, EMB, MID);
    transpose_split<<<dim3(FEAT / 32, MID / 32), dim3(256), 0, stream>>>(
        dec_w2, wd2T_hi, wd2T_lo, SC_W, MID, FEAT);
    norm_codes<<<dim3(KCODE / 4), dim3(256), 0, stream>>>(emb, cn_hi, cn_lo);
    copy_f4<<<dim3((KCODE * EMB / 4 + 255) / 256), dim3(256), 0, stream>>>(
        emb, out_emb, KCODE * EMB / 4);

    // --- G1: x @ w1 partials; split-K=4, 1024 blocks (4/CU), swizzled
    gemm_sk<3, 1><<<dim3(1024), dim3(256), 0, stream>>>(
        x, nullptr, nullptr, w1T_hi, w1T_lo, SC_X,
        scr, nullptr, 0.0f, 0, nullptr, nullptr, nullptr, 0.0f,
        BATCH, MID, FEAT, 2, 2, 1);
    // red1: h = relu(sum * DS_G1 + b1) -> h hi/lo
    reduce_sk<<<dim3(BATCH * MID / 4 / 256), dim3(256), 0, stream>>>(
        scr, 4, BATCH * MID, MID, enc_b1, DS_G1, 1,
        nullptr, h_hi, h_lo, SC_H);

    // --- G2: h @ w2 partials; split-K=4, 512 blocks, swizzled
    gemm_sk<3, 0><<<dim3(512), dim3(256), 0, stream>>>(
        nullptr, h_hi, h_lo, w2T_hi, w2T_lo, 0.0f,
        scr, nullptr, 0.0f, 0, nullptr, nullptr, nullptr, 0.0f,
        BATCH, EMB, MID, 2, 1, 1);
    // red2: encoded = sum * DS_G2 + b2 -> fp32 out + enc hi/lo
    reduce_sk<<<dim3(BATCH * EMB / 4 / 256), dim3(256), 0, stream>>>(
        scr, 4, BATCH * EMB, EMB, enc_b2, DS_G2, 0,
        out_encoded, enc_hi, enc_lo, SC_ENC);

    // --- G3: enc @ cn^T partials; split-K=2, 512 blocks, swizzled
    gemm_sk<3, 0><<<dim3(512), dim3(256), 0, stream>>>(
        nullptr, enc_hi, enc_lo, cn_hi, cn_lo, 0.0f,
        scr, nullptr, 0.0f, 0, nullptr, nullptr, nullptr, 0.0f,
        BATCH, KCODE, EMB, 1, 2, 1);
    // --- argmax over (p0+p1): one-hot, vq_feat, idx (S never materialized)
    argmax_vq2<<<dim3(BATCH / 4), dim3(256), 0, stream>>>(
        scr, BATCH * KCODE, emb, out_onehot, out_vqfeat, idx);

    // --- decoder on codebook only (512 distinct rows), 1-term f16
    gemm_sk<1, 1><<<dim3(KCODE / 128, KCODE / 128), dim3(256), 0, stream>>>(
        emb, nullptr, nullptr, wd1T_hi, wd1T_lo, SC_EMB,
        nullptr, dec_b1, DS_D1, 1, nullptr, tm_hi, tm_lo, SC_TM,
        KCODE, MID, EMB, 0, 0, 0);
    gemm_sk<1, 0><<<dim3(FEAT / 128, KCODE / 128), dim3(256), 0, stream>>>(
        nullptr, tm_hi, tm_lo, wd2T_hi, wd2T_lo, 0.0f,
        nullptr, dec_b2, DS_D2, 1, Dc, nullptr, nullptr, 0.0f,
        KCODE, FEAT, MID, 0, 0, 0);

    // --- decoded[i] = Dcode[idx[i]]
    gather_decoded<<<dim3(BATCH), dim3(256), 0, stream>>>(Dc, idx, out_decoded);
}